// Round 3
// baseline (124.873 us; speedup 1.0000x reference)
//
#include <hip/hip_runtime.h>
#include <cmath>

typedef __attribute__((ext_vector_type(8))) short bf16x8;
typedef __attribute__((ext_vector_type(4))) float f32x4;
typedef unsigned short u16;
typedef unsigned int u32;

#define OUT1OFF 33554432   // 8*128*128*256
#define LDW 264            // padded bf16 row stride

__device__ __forceinline__ u16 f2bf(float f) {
  union { float f; u32 u; } v; v.f = f;
  u32 r = v.u + 0x7fffu + ((v.u >> 16) & 1u);  // RNE
  return (u16)(r >> 16);
}

__device__ __forceinline__ float bf2f(u32 bits16) {
  union { u32 u; float f; } v; v.u = bits16 << 16;
  return v.f;
}

// tanh-form gelu: x * sigmoid(2c(x+0.044715x^3)), max dev from exact ~6e-4
__device__ __forceinline__ float gelu_t(float x) {
  const float x2 = x * x;
  const float z = 1.5957691216057308f * x * fmaf(0.044715f, x2, 1.0f);
  return x / (1.0f + __expf(-z));
}

// ---------------- k1: U = x@Wtop, Y = x@Wbot + b ; W1T bf16 transpose ----------------
__global__ __launch_bounds__(256) void k1_prep(
    const float* __restrict__ x, const float* __restrict__ Wn2e,
    const float* __restrict__ bn2e, const float* __restrict__ W1,
    float* __restrict__ Uw, float* __restrict__ Yw, u16* __restrict__ W1T)
{
  __shared__ float xl[4][256];
  const int t = threadIdx.x;
  const int blk = blockIdx.x;      // 0..255, 4 node-rows each
  const int r0 = blk * 4;
  {
    const int rr = t >> 6, c4 = (t & 63) * 4;
    *(float4*)&xl[rr][c4] = *(const float4*)&x[(r0 + rr) * 256 + c4];
  }
  __syncthreads();
  const int c = t;
  float u0=0.f,u1=0.f,u2=0.f,u3=0.f,y0=0.f,y1=0.f,y2=0.f,y3=0.f;
  #pragma unroll 4
  for (int k = 0; k < 256; ++k) {
    const float wt = Wn2e[k * 256 + c];
    const float wb = Wn2e[(k + 256) * 256 + c];
    const float a0 = xl[0][k], a1 = xl[1][k], a2 = xl[2][k], a3 = xl[3][k];
    u0 = fmaf(a0, wt, u0); u1 = fmaf(a1, wt, u1);
    u2 = fmaf(a2, wt, u2); u3 = fmaf(a3, wt, u3);
    y0 = fmaf(a0, wb, y0); y1 = fmaf(a1, wb, y1);
    y2 = fmaf(a2, wb, y2); y3 = fmaf(a3, wb, y3);
  }
  const float bb = bn2e[c];
  Uw[(r0+0)*256+c]=u0; Uw[(r0+1)*256+c]=u1; Uw[(r0+2)*256+c]=u2; Uw[(r0+3)*256+c]=u3;
  Yw[(r0+0)*256+c]=y0+bb; Yw[(r0+1)*256+c]=y1+bb; Yw[(r0+2)*256+c]=y2+bb; Yw[(r0+3)*256+c]=y3+bb;
  if (blk < 128) W1T[blk * 256 + t] = f2bf(W1[t * 128 + blk]);
}

// ---- k2: fused, 64-row j-tiles. ez -> MFMA (W1 from global) -> e2v,k -> epilogue ----
__global__ __launch_bounds__(512, 8) void k2_fused(
    const float* __restrict__ Uw, const float* __restrict__ Yw,
    const u16* __restrict__ W1T, const float* __restrict__ b1,
    const float* __restrict__ W2, const float* __restrict__ b2p,
    const float* __restrict__ E, float* __restrict__ out)
{
  __shared__ u16 ezLds[64 * LDW];      // 33.8 KB, bf16 ez[jl][k]
  __shared__ float uRow[256];          // phase A: U row; later reused as k[jl]
  __shared__ float psumBuf[2][64];
  const int t = threadIdx.x;
  const int blk2 = blockIdx.x;         // (b*128+i)*2 + h
  const int pair = blk2 >> 1;          // b*128 + i
  const int h = blk2 & 1;
  const int j0 = h * 64;
  const int b = pair >> 7;

  if (t < 64) *(float4*)&uRow[t * 4] = *(const float4*)&Uw[pair * 256 + t * 4];
  __syncthreads();
  // ez = gelu(U[i] + Y[j0+jl]) -> bf16 LDS
  {
    const int c4 = (t & 63) * 4, rw = t >> 6;
    const float u0 = uRow[c4+0], u1 = uRow[c4+1], u2 = uRow[c4+2], u3 = uRow[c4+3];
    #pragma unroll 2
    for (int it = 0; it < 8; ++it) {
      const int jl = it * 8 + rw;
      const float4 yv = *(const float4*)&Yw[(b * 128 + j0 + jl) * 256 + c4];
      const u16 p0 = f2bf(gelu_t(u0 + yv.x));
      const u16 p1 = f2bf(gelu_t(u1 + yv.y));
      const u16 p2 = f2bf(gelu_t(u2 + yv.z));
      const u16 p3 = f2bf(gelu_t(u3 + yv.w));
      uint2 w;
      w.x = (u32)p0 | ((u32)p1 << 16);
      w.y = (u32)p2 | ((u32)p3 << 16);
      *(uint2*)&ezLds[jl * LDW + c4] = w;
    }
  }
  __syncthreads();
  // GEMM2: h = ez @ W1 (B-frags straight from global W1T, L2-resident).
  // 8 waves = 4 M-tiles x 2 N-halves. 16x16x32 bf16 MFMA.
  {
    const int w = t >> 6, l = t & 63;
    const int l15 = l & 15, lh = l >> 4;
    const int wm = w >> 1, wn = w & 1;
    const int kg = lh * 8;
    f32x4 acc[4];
    #pragma unroll
    for (int nt = 0; nt < 4; ++nt) acc[nt] = (f32x4){0.f,0.f,0.f,0.f};
    #pragma unroll
    for (int ks = 0; ks < 8; ++ks) {
      const int k = ks * 32 + kg;
      const bf16x8 a0 = *(const bf16x8*)&ezLds[(wm * 16 + l15) * LDW + k];
      #pragma unroll
      for (int nt = 0; nt < 4; ++nt) {
        const bf16x8 bv = *(const bf16x8*)&W1T[(wn * 64 + nt * 16 + l15) * 256 + k];
        acc[nt] = __builtin_amdgcn_mfma_f32_16x16x32_bf16(a0, bv, acc[nt], 0, 0, 0);
      }
    }
    // GEMM3 partials: e2v_pre[jl] = sum_n relu(h[jl][n]+b1[n]) * W2[n]
    float ps0=0.f, ps1=0.f, ps2=0.f, ps3=0.f;
    #pragma unroll
    for (int nt = 0; nt < 4; ++nt) {
      const int col = wn * 64 + nt * 16 + l15;
      const float bv = b1[col], wv = W2[col];
      ps0 += fmaxf(acc[nt][0] + bv, 0.f) * wv;
      ps1 += fmaxf(acc[nt][1] + bv, 0.f) * wv;
      ps2 += fmaxf(acc[nt][2] + bv, 0.f) * wv;
      ps3 += fmaxf(acc[nt][3] + bv, 0.f) * wv;
    }
    #pragma unroll
    for (int m = 1; m < 16; m <<= 1) {
      ps0 += __shfl_xor(ps0, m, 64);
      ps1 += __shfl_xor(ps1, m, 64);
      ps2 += __shfl_xor(ps2, m, 64);
      ps3 += __shfl_xor(ps3, m, 64);
    }
    if (l15 == 0) {
      const int jb = wm * 16 + lh * 4;
      psumBuf[wn][jb + 0] = ps0;
      psumBuf[wn][jb + 1] = ps1;
      psumBuf[wn][jb + 2] = ps2;
      psumBuf[wn][jb + 3] = ps3;
    }
  }
  __syncthreads();
  // e2v + curvature k per row jl (uRow reused as k[jl])
  if (t < 64) {
    const float e2v = fmaxf(psumBuf[0][t] + psumBuf[1][t] + b2p[0], 0.f);
    out[OUT1OFF + pair * 128 + j0 + t] = e2v;
    float kk = 2.f;
    if (e2v >= 0.2f && e2v < 1.0f) kk -= 2.f * sqrtf(e2v * 1e-9f);
    uRow[t] = kk;
  }
  __syncthreads();
  // epilogue: out0 = ez + 0.5*(k - exp(sigmoid(ez)))*E for this 64x256 slice
  {
    const int rw = t >> 6, c4 = (t & 63) * 4;
    const int eBase = pair * 32768 + j0 * 256;
    #pragma unroll 2
    for (int it = 0; it < 8; ++it) {
      const int jl = it * 8 + rw;
      const float kk = uRow[jl];
      const uint2 ezp = *(const uint2*)&ezLds[jl * LDW + c4];
      const float4 ev = *(const float4*)&E[eBase + jl * 256 + c4];
      const float ez0 = bf2f(ezp.x & 0xffffu), ez1 = bf2f(ezp.x >> 16);
      const float ez2 = bf2f(ezp.y & 0xffffu), ez3 = bf2f(ezp.y >> 16);
      float4 o;
      o.x = ez0 + 0.5f * (kk - __expf(1.f / (1.f + __expf(-ez0)))) * ev.x;
      o.y = ez1 + 0.5f * (kk - __expf(1.f / (1.f + __expf(-ez1)))) * ev.y;
      o.z = ez2 + 0.5f * (kk - __expf(1.f / (1.f + __expf(-ez2)))) * ev.z;
      o.w = ez3 + 0.5f * (kk - __expf(1.f / (1.f + __expf(-ez3)))) * ev.w;
      *(float4*)&out[eBase + jl * 256 + c4] = o;
    }
  }
}

extern "C" void kernel_launch(void* const* d_in, const int* in_sizes, int n_in,
                              void* d_out, int out_size, void* d_ws, size_t ws_size,
                              hipStream_t stream) {
  const float* x    = (const float*)d_in[0];   // [1024, 256]
  const float* E    = (const float*)d_in[1];   // [131072, 256]
  const float* Wn2e = (const float*)d_in[2];   // [512, 256]
  const float* bn2e = (const float*)d_in[3];   // [256]
  const float* W1   = (const float*)d_in[4];   // [256, 128]
  const float* b1   = (const float*)d_in[5];   // [128]
  const float* W2   = (const float*)d_in[6];   // [128]
  const float* b2   = (const float*)d_in[7];   // [1]
  float* out = (float*)d_out;

  float* Uw = (float*)d_ws;                    // [1024, 256] f32
  float* Yw = Uw + 262144;                     // [1024, 256] f32
  u16*  W1T = (u16*)(Yw + 262144);             // [128, 256] bf16

  hipLaunchKernelGGL(k1_prep, dim3(256), dim3(256), 0, stream,
                     x, Wn2e, bn2e, W1, Uw, Yw, W1T);
  hipLaunchKernelGGL(k2_fused, dim3(2048), dim3(512), 0, stream,
                     Uw, Yw, W1T, b1, W2, b2, E, out);
}